// Round 1
// baseline (1527.218 us; speedup 1.0000x reference)
//
#include <hip/hip_runtime.h>
#include <hip/hip_bf16.h>

#define T_LEN 256
#define B_SZ  256
#define EMB   128
#define IN_DIM 384          // 3*EMB
#define UNITS 100
#define GATES 400           // 4*UNITS

// ---------------------------------------------------------------------------
// Kernel 1: embedding gather + input projection  xw[t][b][j] = x[t,b,:]@W[:,j]+b[j]
// Grid: (65536/32, 2 dirs), block 512. 32 rows (same t, consecutive b) staged
// in LDS; thread j (<400) computes column j for all 32 rows. Output bf16.
// ---------------------------------------------------------------------------
__global__ __launch_bounds__(512) void embed_project(
    const int* __restrict__ words, const int* __restrict__ pos, const int* __restrict__ dep,
    const float* __restrict__ Ew, const float* __restrict__ Ep, const float* __restrict__ Ed,
    const float* __restrict__ Wf, const float* __restrict__ bf,
    const float* __restrict__ Wb, const float* __restrict__ bb,
    __hip_bfloat16* __restrict__ xw_f, __hip_bfloat16* __restrict__ xw_b)
{
    const int dir = blockIdx.y;
    const float* W    = dir ? Wb : Wf;
    const float* bias = dir ? bb : bf;
    __hip_bfloat16* out = dir ? xw_b : xw_f;

    const int r0 = blockIdx.x * 32;   // row r = t*256 + b
    const int t  = r0 >> 8;
    const int b0 = r0 & 255;

    __shared__ __align__(16) float xs[32][IN_DIM];
    __shared__ int idx[3][32];

    const int tid = threadIdx.x;
    if (tid < 96) {
        const int which = tid >> 5, i = tid & 31;
        const int* src = (which == 0) ? words : (which == 1) ? pos : dep;
        idx[which][i] = src[(size_t)(b0 + i) * T_LEN + t];
    }
    __syncthreads();

    for (int e = tid; e < 32 * IN_DIM; e += 512) {
        const int i = e / IN_DIM, c = e % IN_DIM;
        float v;
        if (c < EMB)          v = Ew[(size_t)idx[0][i] * EMB + c];
        else if (c < 2 * EMB) v = Ep[(size_t)idx[1][i] * EMB + (c - EMB)];
        else                  v = Ed[(size_t)idx[2][i] * EMB + (c - 2 * EMB)];
        xs[i][c] = v;
    }
    __syncthreads();

    if (tid >= GATES) return;
    const int j = tid;

    float acc[32];
#pragma unroll
    for (int r = 0; r < 32; ++r) acc[r] = 0.f;

    for (int k = 0; k < IN_DIM; k += 4) {
        const float w0 = W[(size_t)(k + 0) * GATES + j];
        const float w1 = W[(size_t)(k + 1) * GATES + j];
        const float w2 = W[(size_t)(k + 2) * GATES + j];
        const float w3 = W[(size_t)(k + 3) * GATES + j];
#pragma unroll
        for (int r = 0; r < 32; ++r) {
            const float4 x4 = *reinterpret_cast<const float4*>(&xs[r][k]);
            acc[r] = fmaf(x4.w, w3, fmaf(x4.z, w2, fmaf(x4.y, w1, fmaf(x4.x, w0, acc[r]))));
        }
    }

    const float bj = bias[j];
#pragma unroll
    for (int r = 0; r < 32; ++r) {
        out[(size_t)(r0 + r) * GATES + j] = __float2bfloat16(acc[r] + bj);
    }
}

// ---------------------------------------------------------------------------
// Kernel 2: masked LSTM recurrence. Grid (256 b, 2 dirs), block 512.
// Thread j<400 holds U[:,j] in registers; h broadcast from LDS; gates by
// threads <100. Outputs h (post-mask) per step to global [t][b][100].
// ---------------------------------------------------------------------------
__global__ __launch_bounds__(512) void lstm_seq(
    const int* __restrict__ words,
    const __hip_bfloat16* __restrict__ xw_f, const __hip_bfloat16* __restrict__ xw_b,
    const float* __restrict__ Uf, const float* __restrict__ Ub,
    float* __restrict__ h_f, float* __restrict__ h_b)
{
    const int b   = blockIdx.x;
    const int dir = blockIdx.y;
    const __hip_bfloat16* xw = dir ? xw_b : xw_f;
    const float* U = dir ? Ub : Uf;
    float* hout    = dir ? h_b : h_f;

    const int j = threadIdx.x;

    __shared__ __align__(16) float h_sh[UNITS];
    __shared__ float z_sh[GATES];

    if (j < UNITS) h_sh[j] = 0.f;

    float u[UNITS];
    if (j < GATES) {
#pragma unroll
        for (int k = 0; k < UNITS; ++k) u[k] = U[(size_t)k * GATES + j];
    }
    float c = 0.f;
    __syncthreads();

    const int t0 = dir ? (T_LEN - 1) : 0;
    const int dt = dir ? -1 : 1;

    float xw_next = 0.f;
    if (j < GATES)
        xw_next = __bfloat162float(xw[((size_t)t0 * B_SZ + b) * GATES + j]);

    for (int s = 0; s < T_LEN; ++s) {
        const int t = t0 + dt * s;
        const float xwv = xw_next;
        if (j < GATES && s + 1 < T_LEN) {
            const int tn = t + dt;
            xw_next = __bfloat162float(xw[((size_t)tn * B_SZ + b) * GATES + j]);
        }

        if (j < GATES) {
            float a0 = 0.f, a1 = 0.f, a2 = 0.f, a3 = 0.f;
            const float4* h4 = reinterpret_cast<const float4*>(h_sh);
#pragma unroll
            for (int k = 0; k < UNITS; k += 4) {
                const float4 hv = h4[k >> 2];
                a0 = fmaf(hv.x, u[k + 0], a0);
                a1 = fmaf(hv.y, u[k + 1], a1);
                a2 = fmaf(hv.z, u[k + 2], a2);
                a3 = fmaf(hv.w, u[k + 3], a3);
            }
            z_sh[j] = xwv + (a0 + a1) + (a2 + a3);
        }
        __syncthreads();

        if (j < UNITS) {
            const float zi = z_sh[j];
            const float zf = z_sh[UNITS + j];
            const float zg = z_sh[2 * UNITS + j];
            const float zo = z_sh[3 * UNITS + j];
            const float ig = 1.f / (1.f + __expf(-zi));
            const float fg = 1.f / (1.f + __expf(-zf));
            const float gg = tanhf(zg);
            const float og = 1.f / (1.f + __expf(-zo));
            const float cn = fg * c + ig * gg;
            const float hn = og * tanhf(cn);
            const bool  m  = words[(size_t)b * T_LEN + t] != 0;
            const float hold = h_sh[j];
            const float h2 = m ? hn : hold;
            c = m ? cn : c;
            h_sh[j] = h2;
            hout[((size_t)t * B_SZ + b) * UNITS + j] = h2;
        }
        __syncthreads();
    }
}

// ---------------------------------------------------------------------------
// Kernel 3: out[b][t] = sigmoid(h_f[t,b,:]·Wo[0:100] + h_b[t,b,:]·Wo[100:200] + bo)
// 4 lanes per output, shuffle reduce. Grid 1024, block 256 (64 outputs/block).
// ---------------------------------------------------------------------------
__global__ __launch_bounds__(256) void out_proj(
    const float* __restrict__ h_f, const float* __restrict__ h_b,
    const float* __restrict__ Wo, const float* __restrict__ bo,
    float* __restrict__ out)
{
    const int tid = threadIdx.x;
    const int g = tid >> 2, sub = tid & 3;
    const int r = blockIdx.x * 64 + g;      // r = t*256 + b
    const int t = r >> 8, b = r & 255;

    const float* hf = h_f + (size_t)r * UNITS;
    const float* hb = h_b + (size_t)r * UNITS;

    float s = 0.f;
    const int k0 = sub * 25;
#pragma unroll
    for (int k = 0; k < 25; ++k) s = fmaf(hf[k0 + k], Wo[k0 + k], s);
#pragma unroll
    for (int k = 0; k < 25; ++k) s = fmaf(hb[k0 + k], Wo[UNITS + k0 + k], s);

    s += __shfl_xor(s, 1);
    s += __shfl_xor(s, 2);

    if (sub == 0)
        out[(size_t)b * T_LEN + t] = 1.f / (1.f + __expf(-(s + bo[0])));
}

// ---------------------------------------------------------------------------
extern "C" void kernel_launch(void* const* d_in, const int* in_sizes, int n_in,
                              void* d_out, int out_size, void* d_ws, size_t ws_size,
                              hipStream_t stream)
{
    const int*   words = (const int*)d_in[0];
    const int*   pos   = (const int*)d_in[1];
    const int*   dep   = (const int*)d_in[2];
    const float* Ew    = (const float*)d_in[3];
    const float* Ep    = (const float*)d_in[4];
    const float* Ed    = (const float*)d_in[5];
    const float* Wf    = (const float*)d_in[6];
    const float* Uf    = (const float*)d_in[7];
    const float* bf    = (const float*)d_in[8];
    const float* Wb    = (const float*)d_in[9];
    const float* Ub    = (const float*)d_in[10];
    const float* bb    = (const float*)d_in[11];
    const float* Wo    = (const float*)d_in[12];
    const float* bo    = (const float*)d_in[13];
    float* out = (float*)d_out;

    char* ws = (char*)d_ws;
    const size_t n_xw = (size_t)T_LEN * B_SZ * GATES;   // 26,214,400
    const size_t n_h  = (size_t)T_LEN * B_SZ * UNITS;   //  6,553,600

    __hip_bfloat16* xw_f = (__hip_bfloat16*)ws; ws += n_xw * sizeof(__hip_bfloat16);
    __hip_bfloat16* xw_b = (__hip_bfloat16*)ws; ws += n_xw * sizeof(__hip_bfloat16);
    float* h_f = (float*)ws; ws += n_h * sizeof(float);
    float* h_b = (float*)ws; ws += n_h * sizeof(float);

    {
        dim3 grid((T_LEN * B_SZ) / 32, 2), block(512);
        embed_project<<<grid, block, 0, stream>>>(words, pos, dep, Ew, Ep, Ed,
                                                  Wf, bf, Wb, bb, xw_f, xw_b);
    }
    {
        dim3 grid(B_SZ, 2), block(512);
        lstm_seq<<<grid, block, 0, stream>>>(words, xw_f, xw_b, Uf, Ub, h_f, h_b);
    }
    {
        dim3 grid((T_LEN * B_SZ) / 64), block(256);
        out_proj<<<grid, block, 0, stream>>>(h_f, h_b, Wo, bo, out);
    }
}

// Round 2
// 813.090 us; speedup vs baseline: 1.8783x; 1.8783x over previous
//
#include <hip/hip_runtime.h>
#include <hip/hip_bf16.h>

#define T_LEN 256
#define B_SZ  256
#define EMB   128
#define IN_DIM 384          // 3*EMB
#define UNITS 100
#define GATES 400           // 4*UNITS
#define NCOL  800           // both directions: [fwd 400 | bwd 400]

typedef __attribute__((ext_vector_type(8))) short short8v;
typedef __attribute__((ext_vector_type(4))) short short4v;
typedef __attribute__((ext_vector_type(4))) float f32x4;

static __device__ __forceinline__ float bf2f(short s) {
    unsigned u = ((unsigned)(unsigned short)s) << 16;
    return __builtin_bit_cast(float, u);
}
static __device__ __forceinline__ short f2bf(float f) {
    return __builtin_bit_cast(short, __float2bfloat16(f));
}
static __device__ __forceinline__ float fast_sigmoid(float x) {
    return 1.f / (1.f + __expf(-x));
}
static __device__ __forceinline__ float fast_tanh(float x) {
    return 1.f - 2.f / (1.f + __expf(2.f * x));
}

// ---------------------------------------------------------------------------
// prep: (a) WbT[c][k] = bf16 transpose of word-part weights, c = dir*400+j
//       (b) P_pos[53][800], P_dep[54][800] (dep absorbs bias)
//       (c) MFMA A/B lane-layout probe -> flag (0 = contiguous-8, 1 = two halves)
// grid 208 blocks x 256
// ---------------------------------------------------------------------------
#define PREP_WT_BLOCKS 100
#define PREP_TAB_BLOCKS 107

__global__ __launch_bounds__(256) void prep(
    const float* __restrict__ Wf, const float* __restrict__ Wb,
    const float* __restrict__ bf_, const float* __restrict__ bb_,
    const float* __restrict__ Ep, const float* __restrict__ Ed,
    __hip_bfloat16* __restrict__ WbT, float* __restrict__ Ppos,
    float* __restrict__ Pdep, int* __restrict__ flag)
{
    __shared__ short Ap[16 * 32];
    __shared__ short Bp[32 * 16];

    const int bx = blockIdx.x, tid = threadIdx.x;

    if (bx < PREP_WT_BLOCKS) {
        const int base = bx * 1024 + tid * 4;
#pragma unroll
        for (int q = 0; q < 4; ++q) {
            const int id = base + q;            // id = c*128 + k
            const int c = id >> 7, k = id & 127;
            const int dir = c >= GATES;
            const int j = c - dir * GATES;
            const float* W = dir ? Wb : Wf;
            WbT[id] = __float2bfloat16(W[k * GATES + j]);
        }
    } else if (bx < PREP_WT_BLOCKS + PREP_TAB_BLOCKS) {
        const int p = bx - PREP_WT_BLOCKS;
        const bool isPos = p < 53;
        const float* Erow = isPos ? (Ep + p * EMB) : (Ed + (size_t)(p - 53) * EMB);
        const int rowoff = isPos ? EMB : 2 * EMB;
        float* dst = isPos ? (Ppos + (size_t)p * NCOL) : (Pdep + (size_t)(p - 53) * NCOL);
        for (int c = tid; c < NCOL; c += 256) {
            const int dir = c >= GATES;
            const int j = c - dir * GATES;
            const float* W = dir ? Wb : Wf;
            float s = 0.f;
            for (int k = 0; k < EMB; ++k)
                s = fmaf(Erow[k], W[(size_t)(rowoff + k) * GATES + j], s);
            if (!isPos) s += (dir ? bb_[j] : bf_[j]);
            dst[c] = s;
        }
    } else {
        // --- MFMA layout probe (wave 0 only) ---
        if (tid < 64) {
            for (int e = tid; e < 512; e += 64) {
                const int m = e >> 5, k = e & 31;
                Ap[e] = f2bf((float)((m * 3 + k * 5) % 7 - 3));
            }
            for (int e = tid; e < 512; e += 64) {
                const int k = e >> 4, n = e & 15;
                Bp[e] = f2bf((float)((k * 7 + n * 3) % 5 - 2));
            }
        }
        __syncthreads();
        if (tid < 64) {
            const int l = tid;
            const int mn = l & 15, grp = l >> 4;
            float ref[4];
#pragma unroll
            for (int i = 0; i < 4; ++i) {
                const int m = grp * 4 + i;
                float s = 0.f;
                for (int k = 0; k < 32; ++k)
                    s += bf2f(Ap[m * 32 + k]) * bf2f(Bp[k * 16 + mn]);
                ref[i] = s;
            }
            short8v a8, b8, a44, b44;
#pragma unroll
            for (int e = 0; e < 8; ++e) {
                const int k8 = grp * 8 + e;
                const int k44 = (e >> 2) * 16 + grp * 4 + (e & 3);
                a8[e]  = Ap[mn * 32 + k8];
                b8[e]  = Bp[k8 * 16 + mn];
                a44[e] = Ap[mn * 32 + k44];
                b44[e] = Bp[k44 * 16 + mn];
            }
            f32x4 z = {0.f, 0.f, 0.f, 0.f};
            f32x4 d8  = __builtin_amdgcn_mfma_f32_16x16x32_bf16(a8,  b8,  z, 0, 0, 0);
            f32x4 d44 = __builtin_amdgcn_mfma_f32_16x16x32_bf16(a44, b44, z, 0, 0, 0);
            const bool ok8  = (d8[0]  == ref[0]) && (d8[1]  == ref[1]) &&
                              (d8[2]  == ref[2]) && (d8[3]  == ref[3]);
            const bool ok44 = (d44[0] == ref[0]) && (d44[1] == ref[1]) &&
                              (d44[2] == ref[2]) && (d44[3] == ref[3]);
            const unsigned long long m8  = __ballot(ok8);
            const unsigned long long m44 = __ballot(ok44);
            if (tid == 0)
                *flag = (m8 == ~0ULL) ? 0 : ((m44 == ~0ULL) ? 1 : 1);
        }
    }
}

// ---------------------------------------------------------------------------
// embed_gemm: xw[r][c] = E_word[words[r]] @ WbT[c] + Ppos[pos[r]][c] + Pdep[dep[r]][c]
// r = t*256+b token index (65536), c in [0,800). Tile 64x160, K=128, 4 waves.
// ---------------------------------------------------------------------------
#define MT 64
#define NT 160

__global__ __launch_bounds__(256) void embed_gemm(
    const int* __restrict__ words, const int* __restrict__ pos, const int* __restrict__ dep,
    const float* __restrict__ Ew, const __hip_bfloat16* __restrict__ WbT,
    const float* __restrict__ Ppos, const float* __restrict__ Pdep,
    const int* __restrict__ flag, __hip_bfloat16* __restrict__ xw)
{
    __shared__ __align__(16) short As[MT * 128];   // swizzled [row][k]
    __shared__ __align__(16) short Bs[NT * 128];   // swizzled [col][k]
    __shared__ int widx[MT], pidx[MT], didx[MT];

    const int tid = threadIdx.x;
    const int bx = blockIdx.x, by = blockIdx.y;
    const int r0 = bx * MT;
    const int t = r0 >> 8, b0 = r0 & 255;
    const int n0 = by * NT;

    if (tid < MT)             widx[tid]          = words[(size_t)(b0 + tid) * T_LEN + t];
    else if (tid < 2 * MT)    pidx[tid - MT]     = pos[(size_t)(b0 + tid - MT) * T_LEN + t];
    else if (tid < 3 * MT)    didx[tid - 2 * MT] = dep[(size_t)(b0 + tid - 2 * MT) * T_LEN + t];
    __syncthreads();

    // stage A: 64 rows x 16 chunks (16B bf16 = 8 elems), f32 -> bf16 on the fly
#pragma unroll
    for (int q = 0; q < 4; ++q) {
        const int ch = tid + q * 256;
        const int row = ch >> 4, c16 = ch & 15;
        const float* src = Ew + (size_t)widx[row] * EMB + c16 * 8;
        const float4 v0 = *reinterpret_cast<const float4*>(src);
        const float4 v1 = *reinterpret_cast<const float4*>(src + 4);
        short8v pk;
        pk[0] = f2bf(v0.x); pk[1] = f2bf(v0.y); pk[2] = f2bf(v0.z); pk[3] = f2bf(v0.w);
        pk[4] = f2bf(v1.x); pk[5] = f2bf(v1.y); pk[6] = f2bf(v1.z); pk[7] = f2bf(v1.w);
        *reinterpret_cast<short8v*>(&As[row * 128 + ((c16 ^ (row & 7)) << 3)]) = pk;
    }
    // stage B: 160 cols x 16 chunks from WbT (already bf16, contiguous per col)
#pragma unroll
    for (int q = 0; q < 10; ++q) {
        const int ch = tid + q * 256;
        const int col = ch >> 4, c16 = ch & 15;
        const short* src = reinterpret_cast<const short*>(WbT) + (size_t)(n0 + col) * 128 + c16 * 8;
        const short8v v = *reinterpret_cast<const short8v*>(src);
        *reinterpret_cast<short8v*>(&Bs[col * 128 + ((c16 ^ (col & 7)) << 3)]) = v;
    }
    __syncthreads();

    const int w = tid >> 6, l = tid & 63;
    const int lr = l & 15, lg = l >> 4;
    const int arow = w * 16 + lr;

    f32x4 acc[10];
#pragma unroll
    for (int ni = 0; ni < 10; ++ni) acc[ni] = f32x4{0.f, 0.f, 0.f, 0.f};

    const int lay = flag[0];

    if (lay == 0) {   // contiguous-8: k = (l>>4)*8 + e  (within 32-wide K step)
#pragma unroll
        for (int kk = 0; kk < 4; ++kk) {
            const int c16 = kk * 4 + lg;
            const short8v a = *reinterpret_cast<const short8v*>(
                &As[arow * 128 + ((c16 ^ (arow & 7)) << 3)]);
#pragma unroll
            for (int ni = 0; ni < 10; ++ni) {
                const int col = ni * 16 + lr;
                const short8v bfr = *reinterpret_cast<const short8v*>(
                    &Bs[col * 128 + ((c16 ^ (col & 7)) << 3)]);
                acc[ni] = __builtin_amdgcn_mfma_f32_16x16x32_bf16(a, bfr, acc[ni], 0, 0, 0);
            }
        }
    } else {          // two K=16 halves: k = (e>>2)*16 + (l>>4)*4 + (e&3)
#pragma unroll
        for (int kk = 0; kk < 4; ++kk) {
            const int ch16 = kk * 4 + (lg >> 1);     // 16B chunk of the low half
            const int inner = (lg & 1) * 4;          // short offset inside chunk
            const int alo_i = arow * 128 + ((ch16 ^ (arow & 7)) << 3) + inner;
            const int ahi_i = arow * 128 + (((ch16 + 2) ^ (arow & 7)) << 3) + inner;
            const short4v alo = *reinterpret_cast<const short4v*>(&As[alo_i]);
            const short4v ahi = *reinterpret_cast<const short4v*>(&As[ahi_i]);
            short8v a;
            a[0] = alo[0]; a[1] = alo[1]; a[2] = alo[2]; a[3] = alo[3];
            a[4] = ahi[0]; a[5] = ahi[1]; a[6] = ahi[2]; a[7] = ahi[3];
#pragma unroll
            for (int ni = 0; ni < 10; ++ni) {
                const int col = ni * 16 + lr;
                const int blo_i = col * 128 + ((ch16 ^ (col & 7)) << 3) + inner;
                const int bhi_i = col * 128 + (((ch16 + 2) ^ (col & 7)) << 3) + inner;
                const short4v blo = *reinterpret_cast<const short4v*>(&Bs[blo_i]);
                const short4v bhi = *reinterpret_cast<const short4v*>(&Bs[bhi_i]);
                short8v b;
                b[0] = blo[0]; b[1] = blo[1]; b[2] = blo[2]; b[3] = blo[3];
                b[4] = bhi[0]; b[5] = bhi[1]; b[6] = bhi[2]; b[7] = bhi[3];
                acc[ni] = __builtin_amdgcn_mfma_f32_16x16x32_bf16(a, b, acc[ni], 0, 0, 0);
            }
        }
    }

    // epilogue: add pos/dep tables (+bias baked in Pdep), store bf16
    const int rbase = w * 16 + lg * 4;
    int pix[4], dix[4];
#pragma unroll
    for (int i = 0; i < 4; ++i) { pix[i] = pidx[rbase + i]; dix[i] = didx[rbase + i]; }
#pragma unroll
    for (int ni = 0; ni < 10; ++ni) {
        const int c = n0 + ni * 16 + lr;
#pragma unroll
        for (int i = 0; i < 4; ++i) {
            const float v = acc[ni][i]
                          + Ppos[(size_t)pix[i] * NCOL + c]
                          + Pdep[(size_t)dix[i] * NCOL + c];
            xw[(size_t)(r0 + rbase + i) * NCOL + c] = __float2bfloat16(v);
        }
    }
}

// ---------------------------------------------------------------------------
// Kernel 2: masked LSTM recurrence (round-1 structure, combined xw layout).
// Grid (256 b, 2 dirs), block 512.
// ---------------------------------------------------------------------------
__global__ __launch_bounds__(512) void lstm_seq(
    const int* __restrict__ words,
    const __hip_bfloat16* __restrict__ xw,
    const float* __restrict__ Uf, const float* __restrict__ Ub,
    float* __restrict__ h_f, float* __restrict__ h_b)
{
    const int b   = blockIdx.x;
    const int dir = blockIdx.y;
    const float* U = dir ? Ub : Uf;
    float* hout    = dir ? h_b : h_f;
    const int coff = dir * GATES;

    const int j = threadIdx.x;

    __shared__ __align__(16) float h_sh[UNITS];
    __shared__ float z_sh[GATES];

    if (j < UNITS) h_sh[j] = 0.f;

    float u[UNITS];
    if (j < GATES) {
#pragma unroll
        for (int k = 0; k < UNITS; ++k) u[k] = U[(size_t)k * GATES + j];
    }
    float c = 0.f;
    __syncthreads();

    const int t0 = dir ? (T_LEN - 1) : 0;
    const int dt = dir ? -1 : 1;

    float xw_next = 0.f;
    if (j < GATES)
        xw_next = __bfloat162float(xw[((size_t)t0 * B_SZ + b) * NCOL + coff + j]);

    for (int s = 0; s < T_LEN; ++s) {
        const int t = t0 + dt * s;
        const float xwv = xw_next;
        if (j < GATES && s + 1 < T_LEN) {
            const int tn = t + dt;
            xw_next = __bfloat162float(xw[((size_t)tn * B_SZ + b) * NCOL + coff + j]);
        }

        if (j < GATES) {
            float a0 = 0.f, a1 = 0.f, a2 = 0.f, a3 = 0.f;
            const float4* h4 = reinterpret_cast<const float4*>(h_sh);
#pragma unroll
            for (int k = 0; k < UNITS; k += 4) {
                const float4 hv = h4[k >> 2];
                a0 = fmaf(hv.x, u[k + 0], a0);
                a1 = fmaf(hv.y, u[k + 1], a1);
                a2 = fmaf(hv.z, u[k + 2], a2);
                a3 = fmaf(hv.w, u[k + 3], a3);
            }
            z_sh[j] = xwv + (a0 + a1) + (a2 + a3);
        }
        __syncthreads();

        if (j < UNITS) {
            const float zi = z_sh[j];
            const float zf = z_sh[UNITS + j];
            const float zg = z_sh[2 * UNITS + j];
            const float zo = z_sh[3 * UNITS + j];
            const float ig = fast_sigmoid(zi);
            const float fg = fast_sigmoid(zf);
            const float gg = fast_tanh(zg);
            const float og = fast_sigmoid(zo);
            const float cn = fg * c + ig * gg;
            const float hn = og * fast_tanh(cn);
            const bool  m  = words[(size_t)b * T_LEN + t] != 0;
            const float hold = h_sh[j];
            const float h2 = m ? hn : hold;
            c = m ? cn : c;
            h_sh[j] = h2;
            hout[((size_t)t * B_SZ + b) * UNITS + j] = h2;
        }
        __syncthreads();
    }
}

// ---------------------------------------------------------------------------
// Kernel 3: out[b][t] = sigmoid(h_f . Wo[0:100] + h_b . Wo[100:200] + bo)
// ---------------------------------------------------------------------------
__global__ __launch_bounds__(256) void out_proj(
    const float* __restrict__ h_f, const float* __restrict__ h_b,
    const float* __restrict__ Wo, const float* __restrict__ bo,
    float* __restrict__ out)
{
    const int tid = threadIdx.x;
    const int g = tid >> 2, sub = tid & 3;
    const int r = blockIdx.x * 64 + g;      // r = t*256 + b
    const int t = r >> 8, b = r & 255;

    const float* hf = h_f + (size_t)r * UNITS;
    const float* hb = h_b + (size_t)r * UNITS;

    float s = 0.f;
    const int k0 = sub * 25;
#pragma unroll
    for (int k = 0; k < 25; ++k) s = fmaf(hf[k0 + k], Wo[k0 + k], s);
#pragma unroll
    for (int k = 0; k < 25; ++k) s = fmaf(hb[k0 + k], Wo[UNITS + k0 + k], s);

    s += __shfl_xor(s, 1);
    s += __shfl_xor(s, 2);

    if (sub == 0)
        out[(size_t)b * T_LEN + t] = 1.f / (1.f + __expf(-(s + bo[0])));
}

// ---------------------------------------------------------------------------
extern "C" void kernel_launch(void* const* d_in, const int* in_sizes, int n_in,
                              void* d_out, int out_size, void* d_ws, size_t ws_size,
                              hipStream_t stream)
{
    const int*   words = (const int*)d_in[0];
    const int*   pos   = (const int*)d_in[1];
    const int*   dep   = (const int*)d_in[2];
    const float* Ew    = (const float*)d_in[3];
    const float* Ep    = (const float*)d_in[4];
    const float* Ed    = (const float*)d_in[5];
    const float* Wf    = (const float*)d_in[6];
    const float* Uf    = (const float*)d_in[7];
    const float* bf_   = (const float*)d_in[8];
    const float* Wb    = (const float*)d_in[9];
    const float* Ub    = (const float*)d_in[10];
    const float* bb_   = (const float*)d_in[11];
    const float* Wo    = (const float*)d_in[12];
    const float* bo    = (const float*)d_in[13];
    float* out = (float*)d_out;

    auto alignup = [](size_t x) { return (x + 255) & ~(size_t)255; };
    char* p = (char*)d_ws;
    __hip_bfloat16* xw = (__hip_bfloat16*)p;  p += alignup((size_t)T_LEN * B_SZ * NCOL * 2);
    float* h_f = (float*)p;                   p += alignup((size_t)T_LEN * B_SZ * UNITS * 4);
    float* h_b = (float*)p;                   p += alignup((size_t)T_LEN * B_SZ * UNITS * 4);
    __hip_bfloat16* WbT = (__hip_bfloat16*)p; p += alignup((size_t)NCOL * 128 * 2);
    float* Ppos = (float*)p;                  p += alignup((size_t)53 * NCOL * 4);
    float* Pdep = (float*)p;                  p += alignup((size_t)54 * NCOL * 4);
    int* flag = (int*)p;

    prep<<<dim3(PREP_WT_BLOCKS + PREP_TAB_BLOCKS + 1), 256, 0, stream>>>(
        Wf, Wb, bf_, bb_, Ep, Ed, WbT, Ppos, Pdep, flag);

    embed_gemm<<<dim3((T_LEN * B_SZ) / MT, NCOL / NT), 256, 0, stream>>>(
        words, pos, dep, Ew, WbT, Ppos, Pdep, flag, xw);

    lstm_seq<<<dim3(B_SZ, 2), 512, 0, stream>>>(words, xw, Uf, Ub, h_f, h_b);

    out_proj<<<dim3((T_LEN * B_SZ) / 64), 256, 0, stream>>>(h_f, h_b, Wo, bo, out);
}